// Round 1
// baseline (269.985 us; speedup 1.0000x reference)
//
#include <hip/hip_runtime.h>
#include <hip/hip_bf16.h>
#include <cstdint>

#define D 128

__device__ __forceinline__ float bf2f(unsigned short u) {
    union { unsigned int i; float f; } x; x.i = ((unsigned int)u) << 16; return x.f;
}
__device__ __forceinline__ unsigned short f2bf(float f) {
    union { float f; unsigned int i; } x; x.f = f;
    unsigned int r = x.i + 0x7FFFu + ((x.i >> 16) & 1u);
    return (unsigned short)(r >> 16);
}

// Detect whether edge_index arrived as int64 (little-endian: odd 32-bit words all 0)
__global__ void detect_i64(const int* __restrict__ eidx, int nPairs, int* __restrict__ flag) {
    __shared__ int anyNonZero;
    if (threadIdx.x == 0) anyNonZero = 0;
    __syncthreads();
    int cnt = nPairs < 2048 ? nPairs : 2048;
    int local = 0;
    for (int i = threadIdx.x; i < cnt; i += 256)
        if (eidx[2 * i + 1] != 0) local = 1;
    if (local) anyNonZero = 1;
    __syncthreads();
    if (threadIdx.x == 0) *flag = (anyNonZero == 0) ? 1 : 0;
}

// U = X @ W1[0:128,:], V = X @ W1[128:256,:]  (fp32 accumulate, bf16 store)
// 64 nodes x 64 cols per block, 256 threads, 4x4 per thread.
// Xs is k-major with an XOR swizzle on the node column to avoid transpose-store bank conflicts.
__global__ __launch_bounds__(256) void uv_gemm(
    const float* __restrict__ X, const float* __restrict__ W1,
    unsigned short* __restrict__ U, unsigned short* __restrict__ V, int nNodes)
{
    __shared__ float Xs[128][64];   // [k][node^swz]
    __shared__ float Ws[128][64];   // [k][col]
    const int t = threadIdx.x;
    const int node0 = blockIdx.x * 64;
    const int cb = blockIdx.y;                 // 0,1 -> U cols 0/64 ; 2,3 -> V cols 0/64
    const float* Wsrc = W1 + (size_t)(cb >> 1) * 128 * D + (cb & 1) * 64;
    unsigned short* O = (cb >> 1) ? V : U;
    const int colbase = (cb & 1) * 64;

    // stage X tile transposed (k-major), swizzled
#pragma unroll
    for (int i = 0; i < 8; ++i) {
        int f = t + i * 256;                   // float4 id 0..2047
        int n = f >> 5;                        // node within tile
        int k4 = (f & 31) << 2;                // k base
        float4 x = make_float4(0.f, 0.f, 0.f, 0.f);
        if (node0 + n < nNodes)
            x = *reinterpret_cast<const float4*>(X + (size_t)(node0 + n) * D + k4);
        int col = n ^ (((k4 >> 2) & 7) << 2);  // (k>>2) identical for the 4 j's
        Xs[k4 + 0][col] = x.x;
        Xs[k4 + 1][col] = x.y;
        Xs[k4 + 2][col] = x.z;
        Xs[k4 + 3][col] = x.w;
    }
    // stage W tile (already k-major in global)
#pragma unroll
    for (int i = 0; i < 8; ++i) {
        int f = t + i * 256;                   // 2048 float4
        int k = f >> 4;
        int c4 = (f & 15) << 2;
        *reinterpret_cast<float4*>(&Ws[k][c4]) =
            *reinterpret_cast<const float4*>(Wsrc + (size_t)k * D + c4);
    }
    __syncthreads();

    const int tr4 = (t & 15) << 2;             // node group base
    const int tc4 = (t >> 4) << 2;             // col group base
    float4 acc0 = make_float4(0, 0, 0, 0), acc1 = acc0, acc2 = acc0, acc3 = acc0;

#pragma unroll 4
    for (int k = 0; k < 128; ++k) {
        const int sw = ((k >> 2) & 7) << 2;
        const float4 xv = *reinterpret_cast<const float4*>(&Xs[k][tr4 ^ sw]);
        const float4 wv = *reinterpret_cast<const float4*>(&Ws[k][tc4]);
        acc0.x += xv.x * wv.x; acc0.y += xv.x * wv.y; acc0.z += xv.x * wv.z; acc0.w += xv.x * wv.w;
        acc1.x += xv.y * wv.x; acc1.y += xv.y * wv.y; acc1.z += xv.y * wv.z; acc1.w += xv.y * wv.w;
        acc2.x += xv.z * wv.x; acc2.y += xv.z * wv.y; acc2.z += xv.z * wv.z; acc2.w += xv.z * wv.w;
        acc3.x += xv.w * wv.x; acc3.y += xv.w * wv.y; acc3.z += xv.w * wv.z; acc3.w += xv.w * wv.w;
    }

    const float4 accs[4] = {acc0, acc1, acc2, acc3};
#pragma unroll
    for (int i = 0; i < 4; ++i) {
        int node = node0 + tr4 + i;
        if (node < nNodes) {
            ushort4 o;
            o.x = f2bf(accs[i].x); o.y = f2bf(accs[i].y);
            o.z = f2bf(accs[i].z); o.w = f2bf(accs[i].w);
            *reinterpret_cast<ushort4*>(O + (size_t)node * D + colbase + tc4) = o;
        }
    }
}

// One edge per half-wave (32 lanes x 4 dims).
__global__ __launch_bounds__(256) void edge_attn(
    const int* __restrict__ eidx, const unsigned short* __restrict__ U,
    const unsigned short* __restrict__ V, const float* __restrict__ b1,
    const float* __restrict__ W2, const float* __restrict__ b2,
    const int* __restrict__ i64flag, float* __restrict__ out,
    int nEdges, int nNodes)
{
    const int t = threadIdx.x;
    const int lane = t & 31;
    const int e = blockIdx.x * 8 + (t >> 5);
    if (e >= nEdges) return;
    const int is64 = i64flag ? *i64flag : 0;
    size_t sOff = is64 ? (size_t)2 * e : (size_t)e;
    size_t dOff = is64 ? (size_t)2 * ((size_t)nEdges + e) : (size_t)nEdges + e;
    int si = eidx[sOff];
    int di = eidx[dOff];
    si = min(max(si, 0), nNodes - 1);
    di = min(max(di, 0), nNodes - 1);

    const int d0 = lane * 4;
    ushort4 ur = *reinterpret_cast<const ushort4*>(U + (size_t)si * D + d0);
    ushort4 vr = *reinterpret_cast<const ushort4*>(V + (size_t)di * D + d0);
    float4 bv = *reinterpret_cast<const float4*>(b1 + d0);
    float h0 = fmaxf(bf2f(ur.x) + bf2f(vr.x) + bv.x, 0.f);
    float h1 = fmaxf(bf2f(ur.y) + bf2f(vr.y) + bv.y, 0.f);
    float h2 = fmaxf(bf2f(ur.z) + bf2f(vr.z) + bv.z, 0.f);
    float h3 = fmaxf(bf2f(ur.w) + bf2f(vr.w) + bv.w, 0.f);
    float4 wa = *reinterpret_cast<const float4*>(W2 + d0 * 2);      // rows d0, d0+1
    float4 wb = *reinterpret_cast<const float4*>(W2 + d0 * 2 + 4);  // rows d0+2, d0+3
    float s0 = h0 * wa.x + h1 * wa.z + h2 * wb.x + h3 * wb.z;
    float s1 = h0 * wa.y + h1 * wa.w + h2 * wb.y + h3 * wb.w;
#pragma unroll
    for (int m = 16; m; m >>= 1) {
        s0 += __shfl_xor(s0, m);
        s1 += __shfl_xor(s1, m);
    }
    if (lane == 0) {
        s0 += b2[0]; s1 += b2[1];
        float mx = fmaxf(s0, s1);
        float e0 = __expf(s0 - mx), e1 = __expf(s1 - mx);
        float r = 1.f / (e0 + e1);
        out[e] = e0 * r;
        out[(size_t)nEdges + e] = e1 * r;
    }
}

// Fallback if workspace is too small: compute h directly per edge (slow but correct).
__global__ __launch_bounds__(256) void edge_attn_direct(
    const int* __restrict__ eidx, const float* __restrict__ X,
    const float* __restrict__ W1, const float* __restrict__ b1,
    const float* __restrict__ W2, const float* __restrict__ b2,
    const int* __restrict__ i64flag, float* __restrict__ out,
    int nEdges, int nNodes)
{
    const int t = threadIdx.x;
    const int lane = t & 31;
    const int e = blockIdx.x * 8 + (t >> 5);
    if (e >= nEdges) return;
    const int is64 = i64flag ? *i64flag : 0;
    size_t sOff = is64 ? (size_t)2 * e : (size_t)e;
    size_t dOff = is64 ? (size_t)2 * ((size_t)nEdges + e) : (size_t)nEdges + e;
    int si = min(max(eidx[sOff], 0), nNodes - 1);
    int di = min(max(eidx[dOff], 0), nNodes - 1);

    const int j0 = lane * 4;
    float4 bv = *reinterpret_cast<const float4*>(b1 + j0);
    float a0 = bv.x, a1 = bv.y, a2 = bv.z, a3 = bv.w;
    const float* xs = X + (size_t)si * D;
    const float* xd = X + (size_t)di * D;
    for (int k = 0; k < 128; ++k) {
        float s = xs[k];
        float4 w = *reinterpret_cast<const float4*>(W1 + (size_t)k * D + j0);
        a0 += s * w.x; a1 += s * w.y; a2 += s * w.z; a3 += s * w.w;
        float d = xd[k];
        float4 w2r = *reinterpret_cast<const float4*>(W1 + (size_t)(k + 128) * D + j0);
        a0 += d * w2r.x; a1 += d * w2r.y; a2 += d * w2r.z; a3 += d * w2r.w;
    }
    a0 = fmaxf(a0, 0.f); a1 = fmaxf(a1, 0.f); a2 = fmaxf(a2, 0.f); a3 = fmaxf(a3, 0.f);
    float4 wa = *reinterpret_cast<const float4*>(W2 + j0 * 2);
    float4 wb = *reinterpret_cast<const float4*>(W2 + j0 * 2 + 4);
    float s0 = a0 * wa.x + a1 * wa.z + a2 * wb.x + a3 * wb.z;
    float s1 = a0 * wa.y + a1 * wa.w + a2 * wb.y + a3 * wb.w;
#pragma unroll
    for (int m = 16; m; m >>= 1) {
        s0 += __shfl_xor(s0, m);
        s1 += __shfl_xor(s1, m);
    }
    if (lane == 0) {
        s0 += b2[0]; s1 += b2[1];
        float mx = fmaxf(s0, s1);
        float e0 = __expf(s0 - mx), e1 = __expf(s1 - mx);
        float r = 1.f / (e0 + e1);
        out[e] = e0 * r;
        out[(size_t)nEdges + e] = e1 * r;
    }
}

extern "C" void kernel_launch(void* const* d_in, const int* in_sizes, int n_in,
                              void* d_out, int out_size, void* d_ws, size_t ws_size,
                              hipStream_t stream)
{
    const float* X   = (const float*)d_in[0];
    const int*   eix = (const int*)d_in[1];
    const float* W1  = (const float*)d_in[2];
    const float* b1  = (const float*)d_in[3];
    const float* W2  = (const float*)d_in[4];
    const float* b2  = (const float*)d_in[5];
    float* out = (float*)d_out;

    const int nNodes = in_sizes[0] / D;
    const int nEdges = in_sizes[1] / 2;
    const size_t uvElems = (size_t)nNodes * D;
    const size_t uvBytes = uvElems * sizeof(unsigned short);
    const int nbEdge = (nEdges + 7) / 8;

    if (ws_size >= 2 * uvBytes + 16) {
        unsigned short* U = (unsigned short*)d_ws;
        unsigned short* V = U + uvElems;
        int* flag = (int*)((char*)d_ws + 2 * uvBytes);
        detect_i64<<<1, 256, 0, stream>>>(eix, nEdges, flag);
        dim3 g((nNodes + 63) / 64, 4);
        uv_gemm<<<g, 256, 0, stream>>>(X, W1, U, V, nNodes);
        edge_attn<<<nbEdge, 256, 0, stream>>>(eix, U, V, b1, W2, b2, flag, out, nEdges, nNodes);
    } else {
        int* flag = (ws_size >= 4) ? (int*)d_ws : nullptr;
        if (flag) detect_i64<<<1, 256, 0, stream>>>(eix, nEdges, flag);
        edge_attn_direct<<<nbEdge, 256, 0, stream>>>(eix, X, W1, b1, W2, b2, flag, out, nEdges, nNodes);
    }
}

// Round 2
// 181.513 us; speedup vs baseline: 1.4874x; 1.4874x over previous
//
#include <hip/hip_runtime.h>
#include <hip/hip_bf16.h>
#include <cstdint>

#define D 128

typedef __attribute__((ext_vector_type(8))) short short8v;
typedef __attribute__((ext_vector_type(4))) float float4v;

__device__ __forceinline__ float bf2f(unsigned short u) {
    union { unsigned int i; float f; } x; x.i = ((unsigned int)u) << 16; return x.f;
}
__device__ __forceinline__ unsigned short f2bf(float f) {
    union { float f; unsigned int i; } x; x.f = f;
    unsigned int r = x.i + 0x7FFFu + ((x.i >> 16) & 1u);
    return (unsigned short)(r >> 16);
}

// Detect whether edge_index arrived as int64 (little-endian: odd 32-bit words all 0)
__global__ void detect_i64(const int* __restrict__ eidx, int nPairs, int* __restrict__ flag) {
    __shared__ int anyNonZero;
    if (threadIdx.x == 0) anyNonZero = 0;
    __syncthreads();
    int cnt = nPairs < 2048 ? nPairs : 2048;
    int local = 0;
    for (int i = threadIdx.x; i < cnt; i += 256)
        if (eidx[2 * i + 1] != 0) local = 1;
    if (local) anyNonZero = 1;
    __syncthreads();
    if (threadIdx.x == 0) *flag = (anyNonZero == 0) ? 1 : 0;
}

// W1 (fp32 [256][128]) -> Bc (bf16, [n=256][k=128], k-contiguous per output column)
// column n<128 -> U col n (uses W1 rows 0..127); n>=128 -> V col n-128 (W1 rows 128..255)
__global__ __launch_bounds__(256) void wcvt(const float* __restrict__ W1,
                                            unsigned short* __restrict__ Bc) {
    int i = blockIdx.x * 256 + threadIdx.x;   // 0..32767
    int n = i >> 7, k = i & 127;
    float v = W1[(size_t)((n < 128) ? k : k + 128) * D + (n & 127)];
    Bc[i] = f2bf(v);
}

// U|V = X @ W1 via bf16 MFMA. No LDS: B-frags from L2-resident Bc, A-frags
// straight from X (f32->bf16 in regs). Block = 64 nodes x 256 cols, 4 waves,
// wave w owns cols w*64..w*64+63.
__global__ __launch_bounds__(256) void uv_mfma(
    const float* __restrict__ X, const unsigned short* __restrict__ Bc,
    unsigned short* __restrict__ U, unsigned short* __restrict__ V, int nNodes)
{
    const int t = threadIdx.x;
    const int wave = t >> 6;
    const int l = t & 63;
    const int lr = l & 15;          // A row / B col / C col within 16x16 tile
    const int lk = l >> 4;          // k-group (A,B) / row-group (C)
    const int node0 = blockIdx.x * 64;
    const int n0w = wave * 64;

    // B fragments: [nt][ks], lane holds B[k = ks*32 + lk*8 + j][col = n0w+nt*16+lr]
    short8v bf[4][4];
#pragma unroll
    for (int nt = 0; nt < 4; ++nt)
#pragma unroll
        for (int ks = 0; ks < 4; ++ks)
            bf[nt][ks] = *reinterpret_cast<const short8v*>(
                Bc + (size_t)(n0w + nt * 16 + lr) * D + ks * 32 + lk * 8);

#pragma unroll
    for (int mt = 0; mt < 4; ++mt) {
        const int row = node0 + mt * 16 + lr;
        const int rowc = row < nNodes ? row : nNodes - 1;
        const float* xp = X + (size_t)rowc * D;
        short8v af[4];
#pragma unroll
        for (int ks = 0; ks < 4; ++ks) {
            float4 x0 = *reinterpret_cast<const float4*>(xp + ks * 32 + lk * 8);
            float4 x1 = *reinterpret_cast<const float4*>(xp + ks * 32 + lk * 8 + 4);
            short8v a;
            a[0] = (short)f2bf(x0.x); a[1] = (short)f2bf(x0.y);
            a[2] = (short)f2bf(x0.z); a[3] = (short)f2bf(x0.w);
            a[4] = (short)f2bf(x1.x); a[5] = (short)f2bf(x1.y);
            a[6] = (short)f2bf(x1.z); a[7] = (short)f2bf(x1.w);
            af[ks] = a;
        }
        float4v acc[4];
#pragma unroll
        for (int nt = 0; nt < 4; ++nt) {
            acc[nt] = (float4v){0.f, 0.f, 0.f, 0.f};
#pragma unroll
            for (int ks = 0; ks < 4; ++ks)
                acc[nt] = __builtin_amdgcn_mfma_f32_16x16x32_bf16(
                    af[ks], bf[nt][ks], acc[nt], 0, 0, 0);
        }
        // C layout: col = lane&15, row = (lane>>4)*4 + r   [m89/m91 verified]
#pragma unroll
        for (int nt = 0; nt < 4; ++nt) {
            const int col = n0w + nt * 16 + lr;
            unsigned short* const base = (col < 128) ? (U + col) : (V + (col - 128));
#pragma unroll
            for (int r = 0; r < 4; ++r) {
                const int orow = node0 + mt * 16 + lk * 4 + r;
                if (orow < nNodes)
                    base[(size_t)orow * D] = f2bf(acc[nt][r]);
            }
        }
    }
}

// One edge per 16 lanes (8 dims/lane, 16B gathers), 4 edges per group for MLP.
__global__ __launch_bounds__(256) void edge_attn(
    const int* __restrict__ eidx, const unsigned short* __restrict__ U,
    const unsigned short* __restrict__ V, const float* __restrict__ b1,
    const float* __restrict__ W2, const float* __restrict__ b2,
    const int* __restrict__ i64flag, float* __restrict__ out,
    int nEdges, int nNodes)
{
    const int t = threadIdx.x;
    const int g = t >> 4;
    const int lane = t & 15;
    const int ebase = (blockIdx.x * 16 + g) * 4;
    if (ebase >= nEdges) return;
    const int is64 = *i64flag;

    int si[4], di[4];
#pragma unroll
    for (int i = 0; i < 4; ++i) {
        int e = ebase + i; if (e >= nEdges) e = nEdges - 1;
        size_t sOff = is64 ? (size_t)2 * e : (size_t)e;
        size_t dOff = is64 ? (size_t)2 * ((size_t)nEdges + e) : (size_t)nEdges + e;
        si[i] = eidx[sOff];
        di[i] = eidx[dOff];
        si[i] = min(max(si[i], 0), nNodes - 1);
        di[i] = min(max(di[i], 0), nNodes - 1);
    }
    // issue all 8 gathers before any compute (MLP)
    uint4 u[4], v[4];
#pragma unroll
    for (int i = 0; i < 4; ++i)
        u[i] = *reinterpret_cast<const uint4*>(U + (size_t)si[i] * D + lane * 8);
#pragma unroll
    for (int i = 0; i < 4; ++i)
        v[i] = *reinterpret_cast<const uint4*>(V + (size_t)di[i] * D + lane * 8);

    float4 b1a = *reinterpret_cast<const float4*>(b1 + lane * 8);
    float4 b1b = *reinterpret_cast<const float4*>(b1 + lane * 8 + 4);
    // W2 rows j0..j0+7 (2 floats each) = 4 float4
    float4 w0 = *reinterpret_cast<const float4*>(W2 + lane * 16);
    float4 w1 = *reinterpret_cast<const float4*>(W2 + lane * 16 + 4);
    float4 w2 = *reinterpret_cast<const float4*>(W2 + lane * 16 + 8);
    float4 w3 = *reinterpret_cast<const float4*>(W2 + lane * 16 + 12);
    const float bb0 = b2[0], bb1 = b2[1];

#pragma unroll
    for (int i = 0; i < 4; ++i) {
        const unsigned short* up = reinterpret_cast<const unsigned short*>(&u[i]);
        const unsigned short* vp = reinterpret_cast<const unsigned short*>(&v[i]);
        const float bv[8] = {b1a.x, b1a.y, b1a.z, b1a.w, b1b.x, b1b.y, b1b.z, b1b.w};
        const float wc[16] = {w0.x, w0.y, w0.z, w0.w, w1.x, w1.y, w1.z, w1.w,
                              w2.x, w2.y, w2.z, w2.w, w3.x, w3.y, w3.z, w3.w};
        float s0 = 0.f, s1 = 0.f;
#pragma unroll
        for (int j = 0; j < 8; ++j) {
            float h = fmaxf(bf2f(up[j]) + bf2f(vp[j]) + bv[j], 0.f);
            s0 += h * wc[2 * j];
            s1 += h * wc[2 * j + 1];
        }
#pragma unroll
        for (int m = 8; m; m >>= 1) {
            s0 += __shfl_xor(s0, m);
            s1 += __shfl_xor(s1, m);
        }
        if (lane == 0 && ebase + i < nEdges) {
            const int e = ebase + i;
            float a0 = s0 + bb0, a1 = s1 + bb1;
            float mx = fmaxf(a0, a1);
            float e0 = __expf(a0 - mx), e1 = __expf(a1 - mx);
            float r = 1.f / (e0 + e1);
            out[e] = e0 * r;
            out[(size_t)nEdges + e] = e1 * r;
        }
    }
}

// Fallback if workspace is too small: compute h directly per edge (slow but correct).
__global__ __launch_bounds__(256) void edge_attn_direct(
    const int* __restrict__ eidx, const float* __restrict__ X,
    const float* __restrict__ W1, const float* __restrict__ b1,
    const float* __restrict__ W2, const float* __restrict__ b2,
    const int* __restrict__ i64flag, float* __restrict__ out,
    int nEdges, int nNodes)
{
    const int t = threadIdx.x;
    const int lane = t & 31;
    const int e = blockIdx.x * 8 + (t >> 5);
    if (e >= nEdges) return;
    const int is64 = i64flag ? *i64flag : 0;
    size_t sOff = is64 ? (size_t)2 * e : (size_t)e;
    size_t dOff = is64 ? (size_t)2 * ((size_t)nEdges + e) : (size_t)nEdges + e;
    int si = min(max(eidx[sOff], 0), nNodes - 1);
    int di = min(max(eidx[dOff], 0), nNodes - 1);

    const int j0 = lane * 4;
    float4 bv = *reinterpret_cast<const float4*>(b1 + j0);
    float a0 = bv.x, a1 = bv.y, a2 = bv.z, a3 = bv.w;
    const float* xs = X + (size_t)si * D;
    const float* xd = X + (size_t)di * D;
    for (int k = 0; k < 128; ++k) {
        float s = xs[k];
        float4 w = *reinterpret_cast<const float4*>(W1 + (size_t)k * D + j0);
        a0 += s * w.x; a1 += s * w.y; a2 += s * w.z; a3 += s * w.w;
        float d = xd[k];
        float4 w2r = *reinterpret_cast<const float4*>(W1 + (size_t)(k + 128) * D + j0);
        a0 += d * w2r.x; a1 += d * w2r.y; a2 += d * w2r.z; a3 += d * w2r.w;
    }
    a0 = fmaxf(a0, 0.f); a1 = fmaxf(a1, 0.f); a2 = fmaxf(a2, 0.f); a3 = fmaxf(a3, 0.f);
    float4 wa = *reinterpret_cast<const float4*>(W2 + j0 * 2);
    float4 wb = *reinterpret_cast<const float4*>(W2 + j0 * 2 + 4);
    float s0 = a0 * wa.x + a1 * wa.z + a2 * wb.x + a3 * wb.z;
    float s1 = a0 * wa.y + a1 * wa.w + a2 * wb.y + a3 * wb.w;
#pragma unroll
    for (int m = 16; m; m >>= 1) {
        s0 += __shfl_xor(s0, m);
        s1 += __shfl_xor(s1, m);
    }
    if (lane == 0) {
        s0 += b2[0]; s1 += b2[1];
        float mx = fmaxf(s0, s1);
        float e0 = __expf(s0 - mx), e1 = __expf(s1 - mx);
        float r = 1.f / (e0 + e1);
        out[e] = e0 * r;
        out[(size_t)nEdges + e] = e1 * r;
    }
}

extern "C" void kernel_launch(void* const* d_in, const int* in_sizes, int n_in,
                              void* d_out, int out_size, void* d_ws, size_t ws_size,
                              hipStream_t stream)
{
    const float* X   = (const float*)d_in[0];
    const int*   eix = (const int*)d_in[1];
    const float* W1  = (const float*)d_in[2];
    const float* b1  = (const float*)d_in[3];
    const float* W2  = (const float*)d_in[4];
    const float* b2  = (const float*)d_in[5];
    float* out = (float*)d_out;

    const int nNodes = in_sizes[0] / D;
    const int nEdges = in_sizes[1] / 2;
    const size_t uvElems = (size_t)nNodes * D;
    const size_t uvBytes = uvElems * sizeof(unsigned short);
    const size_t bcBytes = 256 * D * sizeof(unsigned short);   // 64 KB

    if (ws_size >= bcBytes + 2 * uvBytes + 16) {
        unsigned short* Bc = (unsigned short*)d_ws;
        unsigned short* U  = (unsigned short*)((char*)d_ws + bcBytes);
        unsigned short* V  = U + uvElems;
        int* flag = (int*)((char*)d_ws + bcBytes + 2 * uvBytes);
        detect_i64<<<1, 256, 0, stream>>>(eix, nEdges, flag);
        wcvt<<<(256 * D) / 256, 256, 0, stream>>>(W1, Bc);
        uv_mfma<<<(nNodes + 63) / 64, 256, 0, stream>>>(X, Bc, U, V, nNodes);
        const int nbEdge = (nEdges + 63) / 64;   // 64 edges per block
        edge_attn<<<nbEdge, 256, 0, stream>>>(eix, U, V, b1, W2, b2, flag, out, nEdges, nNodes);
    } else {
        int* flag = (ws_size >= 4) ? (int*)d_ws : nullptr;
        if (flag) detect_i64<<<1, 256, 0, stream>>>(eix, nEdges, flag);
        const int nbEdge = (nEdges + 7) / 8;
        edge_attn_direct<<<nbEdge, 256, 0, stream>>>(eix, X, W1, b1, W2, b2, flag, out, nEdges, nNodes);
    }
}

// Round 3
// 175.931 us; speedup vs baseline: 1.5346x; 1.0317x over previous
//
#include <hip/hip_runtime.h>
#include <hip/hip_bf16.h>
#include <cstdint>

#define D 128

typedef __attribute__((ext_vector_type(8))) short short8v;
typedef __attribute__((ext_vector_type(4))) float float4v;

__device__ __forceinline__ float bf2f(unsigned short u) {
    union { unsigned int i; float f; } x; x.i = ((unsigned int)u) << 16; return x.f;
}
__device__ __forceinline__ unsigned short f2bf(float f) {
    union { float f; unsigned int i; } x; x.f = f;
    unsigned int r = x.i + 0x7FFFu + ((x.i >> 16) & 1u);
    return (unsigned short)(r >> 16);
}

__device__ __forceinline__ void detect_body(const int* __restrict__ eidx, int nPairs,
                                            int* __restrict__ flag) {
    __shared__ int anyNZ;
    if (threadIdx.x == 0) anyNZ = 0;
    __syncthreads();
    int cnt = nPairs < 2048 ? nPairs : 2048;
    int local = 0;
    for (int i = threadIdx.x; i < cnt; i += 256)
        if (eidx[2 * i + 1] != 0) local = 1;
    if (local) anyNZ = 1;
    __syncthreads();
    if (threadIdx.x == 0) *flag = (anyNZ == 0) ? 1 : 0;
}

// blocks 0..127: W1 (fp32) -> Bc (bf16 [n=256][k=128]); block 128: int64 detect.
__global__ __launch_bounds__(256) void prep(
    const float* __restrict__ W1, unsigned short* __restrict__ Bc,
    const int* __restrict__ eidx, int nPairs, int* __restrict__ flag)
{
    if ((int)blockIdx.x < 128) {
        int i = blockIdx.x * 256 + threadIdx.x;
        int n = i >> 7, k = i & 127;
        Bc[i] = f2bf(W1[(size_t)((n < 128) ? k : k + 128) * D + (n & 127)]);
    } else {
        detect_body(eidx, nPairs, flag);
    }
}

__global__ __launch_bounds__(256) void detect_only(
    const int* __restrict__ eidx, int nPairs, int* __restrict__ flag)
{
    detect_body(eidx, nPairs, flag);
}

// U|V = X @ W1 via bf16 MFMA, operands swapped so each lane holds 4 consecutive
// output cols of one node (packed 8B LDS writes), LDS-staged 16B coalesced stores.
__global__ __launch_bounds__(256) void uv_mfma(
    const float* __restrict__ X, const unsigned short* __restrict__ Bc,
    unsigned short* __restrict__ U, unsigned short* __restrict__ V, int nNodes)
{
    __shared__ unsigned short Lds[16][256];
    const int t = threadIdx.x;
    const int wave = t >> 6;
    const int l = t & 63;
    const int lr = l & 15;
    const int lk = l >> 4;
    const int node0 = blockIdx.x * 64;
    const int n0w = wave * 64;

    short8v bf[4][4];
#pragma unroll
    for (int nt = 0; nt < 4; ++nt)
#pragma unroll
        for (int ks = 0; ks < 4; ++ks)
            bf[nt][ks] = *reinterpret_cast<const short8v*>(
                Bc + (size_t)(n0w + nt * 16 + lr) * D + ks * 32 + lk * 8);

#pragma unroll
    for (int mt = 0; mt < 4; ++mt) {
        const int row = node0 + mt * 16 + lr;
        const int rowc = row < nNodes ? row : nNodes - 1;
        const float* xp = X + (size_t)rowc * D;
        short8v af[4];
#pragma unroll
        for (int ks = 0; ks < 4; ++ks) {
            float4 x0 = *reinterpret_cast<const float4*>(xp + ks * 32 + lk * 8);
            float4 x1 = *reinterpret_cast<const float4*>(xp + ks * 32 + lk * 8 + 4);
            short8v a;
            a[0] = (short)f2bf(x0.x); a[1] = (short)f2bf(x0.y);
            a[2] = (short)f2bf(x0.z); a[3] = (short)f2bf(x0.w);
            a[4] = (short)f2bf(x1.x); a[5] = (short)f2bf(x1.y);
            a[6] = (short)f2bf(x1.z); a[7] = (short)f2bf(x1.w);
            af[ks] = a;
        }
        float4v acc[4];
#pragma unroll
        for (int nt = 0; nt < 4; ++nt) {
            acc[nt] = (float4v){0.f, 0.f, 0.f, 0.f};
#pragma unroll
            for (int ks = 0; ks < 4; ++ks)
                acc[nt] = __builtin_amdgcn_mfma_f32_16x16x32_bf16(
                    bf[nt][ks], af[ks], acc[nt], 0, 0, 0);
        }
        if (mt) __syncthreads();
#pragma unroll
        for (int nt = 0; nt < 4; ++nt) {
            int colbase = (n0w + nt * 16 + lk * 4) ^ ((lr & 3) << 4);
            ushort4 o;
            o.x = f2bf(acc[nt][0]); o.y = f2bf(acc[nt][1]);
            o.z = f2bf(acc[nt][2]); o.w = f2bf(acc[nt][3]);
            *reinterpret_cast<ushort4*>(&Lds[lr][colbase]) = o;
        }
        __syncthreads();
#pragma unroll
        for (int cc = 0; cc < 2; ++cc) {
            int rw = (t >> 5) + cc * 8;
            int sub = t & 31;
            int orow = node0 + mt * 16 + rw;
            if (orow < nNodes) {
                int src = (sub * 8) ^ ((rw & 3) << 4);
                uint4 val = *reinterpret_cast<const uint4*>(&Lds[rw][src]);
                unsigned short* dst = (sub < 16 ? U : V) + (size_t)orow * D + (sub & 15) * 8;
                *reinterpret_cast<uint4*>(dst) = val;
            }
        }
    }
}

__global__ __launch_bounds__(256) void edge_attn(
    const int* __restrict__ eidx, const unsigned short* __restrict__ U,
    const unsigned short* __restrict__ V, const float* __restrict__ b1,
    const float* __restrict__ W2, const float* __restrict__ b2,
    const int* __restrict__ i64flag, float* __restrict__ out,
    int nEdges, int nNodes)
{
    const int t = threadIdx.x;
    const int g = t >> 4;
    const int lane = t & 15;
    const int ebase = (blockIdx.x * 16 + g) * 4;
    if (ebase >= nEdges) return;
    const int is64 = *i64flag;
    const bool vec4 = ((nEdges & 3) == 0);

    int si[4], di[4];
    if (vec4) {
        if (!is64) {
            int4 s4 = *reinterpret_cast<const int4*>(eidx + ebase);
            int4 d4 = *reinterpret_cast<const int4*>(eidx + nEdges + ebase);
            si[0] = s4.x; si[1] = s4.y; si[2] = s4.z; si[3] = s4.w;
            di[0] = d4.x; di[1] = d4.y; di[2] = d4.z; di[3] = d4.w;
        } else {
            int4 a = *reinterpret_cast<const int4*>(eidx + 2 * (size_t)ebase);
            int4 b = *reinterpret_cast<const int4*>(eidx + 2 * (size_t)ebase + 4);
            int4 c = *reinterpret_cast<const int4*>(eidx + 2 * ((size_t)nEdges + ebase));
            int4 d = *reinterpret_cast<const int4*>(eidx + 2 * ((size_t)nEdges + ebase) + 4);
            si[0] = a.x; si[1] = a.z; si[2] = b.x; si[3] = b.z;
            di[0] = c.x; di[1] = c.z; di[2] = d.x; di[3] = d.z;
        }
    } else {
#pragma unroll
        for (int i = 0; i < 4; ++i) {
            int e = ebase + i; if (e >= nEdges) e = nEdges - 1;
            size_t sOff = is64 ? (size_t)2 * e : (size_t)e;
            size_t dOff = is64 ? (size_t)2 * ((size_t)nEdges + e) : (size_t)nEdges + e;
            si[i] = eidx[sOff];
            di[i] = eidx[dOff];
        }
    }
#pragma unroll
    for (int i = 0; i < 4; ++i) {
        si[i] = min(max(si[i], 0), nNodes - 1);
        di[i] = min(max(di[i], 0), nNodes - 1);
    }
    uint4 u[4], v[4];
#pragma unroll
    for (int i = 0; i < 4; ++i)
        u[i] = *reinterpret_cast<const uint4*>(U + (size_t)si[i] * D + lane * 8);
#pragma unroll
    for (int i = 0; i < 4; ++i)
        v[i] = *reinterpret_cast<const uint4*>(V + (size_t)di[i] * D + lane * 8);

    float4 b1a = *reinterpret_cast<const float4*>(b1 + lane * 8);
    float4 b1b = *reinterpret_cast<const float4*>(b1 + lane * 8 + 4);
    float4 w0 = *reinterpret_cast<const float4*>(W2 + lane * 16);
    float4 w1 = *reinterpret_cast<const float4*>(W2 + lane * 16 + 4);
    float4 w2 = *reinterpret_cast<const float4*>(W2 + lane * 16 + 8);
    float4 w3 = *reinterpret_cast<const float4*>(W2 + lane * 16 + 12);
    const float bb0 = b2[0], bb1 = b2[1];

#pragma unroll
    for (int i = 0; i < 4; ++i) {
        const unsigned short* up = reinterpret_cast<const unsigned short*>(&u[i]);
        const unsigned short* vp = reinterpret_cast<const unsigned short*>(&v[i]);
        const float bv[8] = {b1a.x, b1a.y, b1a.z, b1a.w, b1b.x, b1b.y, b1b.z, b1b.w};
        const float wc[16] = {w0.x, w0.y, w0.z, w0.w, w1.x, w1.y, w1.z, w1.w,
                              w2.x, w2.y, w2.z, w2.w, w3.x, w3.y, w3.z, w3.w};
        float s0 = 0.f, s1 = 0.f;
#pragma unroll
        for (int j = 0; j < 8; ++j) {
            float h = fmaxf(bf2f(up[j]) + bf2f(vp[j]) + bv[j], 0.f);
            s0 += h * wc[2 * j];
            s1 += h * wc[2 * j + 1];
        }
#pragma unroll
        for (int m = 8; m; m >>= 1) {
            s0 += __shfl_xor(s0, m);
            s1 += __shfl_xor(s1, m);
        }
        if (lane == 0 && ebase + i < nEdges) {
            const int e = ebase + i;
            float a0 = s0 + bb0, a1 = s1 + bb1;
            float mx = fmaxf(a0, a1);
            float e0 = __expf(a0 - mx), e1 = __expf(a1 - mx);
            float r = 1.f / (e0 + e1);
            out[e] = e0 * r;
            out[(size_t)nEdges + e] = e1 * r;
        }
    }
}

__global__ __launch_bounds__(256) void edge_attn_direct(
    const int* __restrict__ eidx, const float* __restrict__ X,
    const float* __restrict__ W1, const float* __restrict__ b1,
    const float* __restrict__ W2, const float* __restrict__ b2,
    const int* __restrict__ i64flag, float* __restrict__ out,
    int nEdges, int nNodes)
{
    const int t = threadIdx.x;
    const int lane = t & 31;
    const int e = blockIdx.x * 8 + (t >> 5);
    if (e >= nEdges) return;
    const int is64 = i64flag ? *i64flag : 0;
    size_t sOff = is64 ? (size_t)2 * e : (size_t)e;
    size_t dOff = is64 ? (size_t)2 * ((size_t)nEdges + e) : (size_t)nEdges + e;
    int si = min(max(eidx[sOff], 0), nNodes - 1);
    int di = min(max(eidx[dOff], 0), nNodes - 1);

    const int j0 = lane * 4;
    float4 bv = *reinterpret_cast<const float4*>(b1 + j0);
    float a0 = bv.x, a1 = bv.y, a2 = bv.z, a3 = bv.w;
    const float* xs = X + (size_t)si * D;
    const float* xd = X + (size_t)di * D;
    for (int k = 0; k < 128; ++k) {
        float s = xs[k];
        float4 w = *reinterpret_cast<const float4*>(W1 + (size_t)k * D + j0);
        a0 += s * w.x; a1 += s * w.y; a2 += s * w.z; a3 += s * w.w;
        float d = xd[k];
        float4 w2r = *reinterpret_cast<const float4*>(W1 + (size_t)(k + 128) * D + j0);
        a0 += d * w2r.x; a1 += d * w2r.y; a2 += d * w2r.z; a3 += d * w2r.w;
    }
    a0 = fmaxf(a0, 0.f); a1 = fmaxf(a1, 0.f); a2 = fmaxf(a2, 0.f); a3 = fmaxf(a3, 0.f);
    float4 wa = *reinterpret_cast<const float4*>(W2 + j0 * 2);
    float4 wb = *reinterpret_cast<const float4*>(W2 + j0 * 2 + 4);
    float s0 = a0 * wa.x + a1 * wa.z + a2 * wb.x + a3 * wb.z;
    float s1 = a0 * wa.y + a1 * wa.w + a2 * wb.y + a3 * wb.w;
#pragma unroll
    for (int m = 16; m; m >>= 1) {
        s0 += __shfl_xor(s0, m);
        s1 += __shfl_xor(s1, m);
    }
    if (lane == 0) {
        s0 += b2[0]; s1 += b2[1];
        float mx = fmaxf(s0, s1);
        float e0 = __expf(s0 - mx), e1 = __expf(s1 - mx);
        float r = 1.f / (e0 + e1);
        out[e] = e0 * r;
        out[(size_t)nEdges + e] = e1 * r;
    }
}

extern "C" void kernel_launch(void* const* d_in, const int* in_sizes, int n_in,
                              void* d_out, int out_size, void* d_ws, size_t ws_size,
                              hipStream_t stream)
{
    const float* X   = (const float*)d_in[0];
    const int*   eix = (const int*)d_in[1];
    const float* W1  = (const float*)d_in[2];
    const float* b1  = (const float*)d_in[3];
    const float* W2  = (const float*)d_in[4];
    const float* b2  = (const float*)d_in[5];
    float* out = (float*)d_out;

    const int nNodes = in_sizes[0] / D;
    const int nEdges = in_sizes[1] / 2;
    const size_t uvElems = (size_t)nNodes * D;
    const size_t uvBytes = uvElems * sizeof(unsigned short);
    const size_t bcBytes = 256 * D * sizeof(unsigned short);   // 64 KB

    if (ws_size >= bcBytes + 2 * uvBytes + 16) {
        unsigned short* Bc = (unsigned short*)d_ws;
        unsigned short* U  = (unsigned short*)((char*)d_ws + bcBytes);
        unsigned short* V  = U + uvElems;
        int* flag = (int*)((char*)d_ws + bcBytes + 2 * uvBytes);
        prep<<<129, 256, 0, stream>>>(W1, Bc, eix, nEdges, flag);
        uv_mfma<<<(nNodes + 63) / 64, 256, 0, stream>>>(X, Bc, U, V, nNodes);
        const int nbEdge = (nEdges + 63) / 64;
        edge_attn<<<nbEdge, 256, 0, stream>>>(eix, U, V, b1, W2, b2, flag, out, nEdges, nNodes);
    } else {
        int* flag = (ws_size >= 4) ? (int*)d_ws : nullptr;
        if (flag) detect_only<<<1, 256, 0, stream>>>(eix, nEdges, flag);
        const int nbEdge = (nEdges + 7) / 8;
        edge_attn_direct<<<nbEdge, 256, 0, stream>>>(eix, X, W1, b1, W2, b2, flag, out, nEdges, nNodes);
    }
}